// Round 4
// baseline (5158.901 us; speedup 1.0000x reference)
//
#include <hip/hip_runtime.h>
#include <hip/hip_bf16.h>
#include <cstdint>
#include <cstddef>

typedef unsigned short u16;
typedef __attribute__((ext_vector_type(8))) __bf16 bf16x8;
typedef __attribute__((ext_vector_type(4))) float f32x4;
typedef __attribute__((ext_vector_type(16))) float f32x16;

#define B_   128
#define T_   256
#define E_   512
#define H_   1024
#define G4_  4096
#define F_   512
#define O_   10
#define NBLK 256

__device__ __forceinline__ u16 f2bf(float f) {
  unsigned int u = __float_as_uint(f);
  u += 0x7FFFu + ((u >> 16) & 1u);
  return (u16)(u >> 16);
}
__device__ __forceinline__ float bf2f(u16 h) {
  return __uint_as_float(((unsigned int)h) << 16);
}
__device__ __forceinline__ float fsigmoid(float x) {
  return 1.f / (1.f + __expf(-x));
}
__device__ __forceinline__ float ftanh(float x) {
  float ax = fabsf(x);
  float t = __expf(-2.f * ax);
  float r = (1.f - t) / (1.f + t);
  return copysignf(r, x);
}
__device__ __forceinline__ bf16x8 pack8(float4 f0, float4 f1) {
  union { bf16x8 v; u16 s[8]; } uu;
  uu.s[0] = f2bf(f0.x); uu.s[1] = f2bf(f0.y); uu.s[2] = f2bf(f0.z); uu.s[3] = f2bf(f0.w);
  uu.s[4] = f2bf(f1.x); uu.s[5] = f2bf(f1.y); uu.s[6] = f2bf(f1.z); uu.s[7] = f2bf(f1.w);
  return uu.v;
}

// async global->LDS, 16B per lane; lds dest wave-uniform base + lane*16
__device__ __forceinline__ void glds16(const void* g, void* l) {
  __builtin_amdgcn_global_load_lds(
      (const __attribute__((address_space(1))) unsigned int*)g,
      (__attribute__((address_space(3))) unsigned int*)l, 16, 0, 0);
}

// ---------------------------------------------------------------- build xe16
// xe16[t*B+b][e] = bf16(emb[x[b][t]][e])   (contiguous per-step slice)
__global__ void build_xe(const int* __restrict__ x, const float* __restrict__ emb,
                         u16* __restrict__ xe16) {
  int id = blockIdx.x * 256 + threadIdx.x;   // over 32768*128 float4-groups
  int row = id >> 7;                          // b*T + t
  int c = (id & 127) << 2;
  int v = x[row];
  int b = row >> 8;                           // T_ = 256
  int t = row & 255;
  const float4 f = *(const float4*)&emb[(size_t)v * E_ + c];
  ushort4 o;
  o.x = f2bf(f.x); o.y = f2bf(f.y); o.z = f2bf(f.z); o.w = f2bf(f.w);
  *(ushort4*)&xe16[((size_t)(t * B_ + b)) * E_ + c] = o;
}

// ---------------------------------------------------------------- topic bias
__global__ void topicb(const float* __restrict__ x_top, const float* __restrict__ w_th,
                       const float* __restrict__ bias, float* __restrict__ tb) {
  int m = blockIdx.x;
  __shared__ float xt[128];
  if (threadIdx.x < 128) xt[threadIdx.x] = x_top[m * 128 + threadIdx.x];
  __syncthreads();
  for (int g = threadIdx.x; g < G4_; g += 256) {
    const float* wr = &w_th[(size_t)g * 128];
    float s = bias[g];
#pragma unroll 8
    for (int k = 0; k < 128; ++k) s += xt[k] * wr[k];
    tb[(size_t)m * G4_ + g] = s;
  }
}

// ---------------------------------------------------------------- grid barrier
__device__ __forceinline__ void gridbar(unsigned* cnt, unsigned target) {
  __syncthreads();   // drains vmcnt/lgkm for all waves of the block
  if (threadIdx.x == 0) {
    __hip_atomic_fetch_add(cnt, 1u, __ATOMIC_RELEASE, __HIP_MEMORY_SCOPE_AGENT);
    while (__hip_atomic_load(cnt, __ATOMIC_RELAXED, __HIP_MEMORY_SCOPE_AGENT) < target)
      __builtin_amdgcn_s_sleep(1);
    (void)__hip_atomic_load(cnt, __ATOMIC_ACQUIRE, __HIP_MEMORY_SCOPE_AGENT);
  }
  __syncthreads();
}

// ---------------------------------------------------------------- persistent LSTM
// 256 blocks x 512 threads. Block = (mg = bid>>7) m-half x (j = bid&127)
// 32 gate-cols. Wave w: mt = w&1 (m-subtile 32 rows), kq = w>>1 (K-quarter
// of 384). B-frags (weights) live in 96 VGPRs per lane, loaded once.
// MFMA 32x32x16. A staged via global_load_lds into [gcol][row] granule
// layout (conflict-free b128), 4-deep ring, counted vmcnt. Partials reduced
// through padded LDS; epilogue 1 cell/lane; cx in registers.
__global__ __launch_bounds__(512, 2) void lstm_persist(
    const u16* __restrict__ xe, u16* __restrict__ h0, u16* __restrict__ h1,
    const float* __restrict__ wih, const float* __restrict__ whh,
    const float* __restrict__ tb, unsigned* __restrict__ cnt) {
  __shared__ __align__(16) u16 Ast[8 * 4 * 1024];     // 65536 B: 8 waves x 4 bufs x 2KB
  __shared__ __align__(16) float pacc[8 * 32 * 36];   // 36864 B: [w][col][row(+4 pad)]

  const int bid = blockIdx.x;
  const int j = bid & 127;
  const int mg = bid >> 7;
  const int tid = threadIdx.x;
  const int w = tid >> 6, l = tid & 63;
  const int mt = w & 1, kq = w >> 1;
  const int mrow0 = mg * 64 + mt * 32;     // this wave's 32 A-rows
  u16* const awbase = &Ast[w * 4096];

  // ---- one-time: B-fragments into registers.
  // B-frag for K-step ks: lane l supplies B[k][n]: n = l&31 -> gate-col,
  // k = ks*16 + (l>>5)*8 + e. W row for col c32: (c32>>3)*1024 + j*8 + (c32&7).
  const int c32 = l & 31;
  const int grow = (c32 >> 3) * H_ + j * 8 + (c32 & 7);
  bf16x8 Bf[24];
#pragma unroll
  for (int ks = 0; ks < 24; ++ks) {
    int k = kq * 384 + ks * 16 + (l >> 5) * 8;
    const float* sf = (k < E_) ? (wih + (size_t)grow * E_ + k)
                               : (whh + (size_t)grow * H_ + (k - E_));
    float4 f0 = *(const float4*)sf;
    float4 f1 = *(const float4*)(sf + 4);
    Bf[ks] = pack8(f0, f1);
  }

  // ---- epilogue cell ownership: lane -> (m_local, hc)
  const int m_local = w * 8 + (l >> 3);    // 0..63
  const int hc = l & 7;
  const int mtE = m_local >> 5;            // which m-subtile my cell is in
  const int rowE = m_local & 31;
  const int mglob = mg * 64 + m_local;
  float tbr[4];
#pragma unroll
  for (int gi = 0; gi < 4; ++gi)
    tbr[gi] = tb[(size_t)mglob * G4_ + gi * H_ + j * 8 + hc];
  float cx = 0.f;

  for (int t = 0; t < T_; ++t) {
    const u16* hin  = (t & 1) ? h1 : h0;
    u16*       hout = (t & 1) ? h0 : h1;

    // stage chunk cs (32 rows x 32 k) into ring buf; LDS layout: granule
    // gidx = gcol*32 + r at offset gidx*16B; DMA writes linear in lane
    // order, so lane i fetches the granule belonging at position u*64+i.
    auto stage = [&](int cs, int buf) {
      int kglob = kq * 384 + cs * 32;
      u16* ldst = awbase + buf * 1024;
#pragma unroll
      for (int u = 0; u < 2; ++u) {
        int gidx = u * 64 + l;
        int gcol = gidx >> 5;              // 0..3
        int r = gidx & 31;
        int k = kglob + gcol * 8;
        const u16* src;
        if (kglob < E_) src = xe + ((size_t)(t * B_) + mrow0 + r) * E_ + k;
        else            src = hin + (size_t)(mrow0 + r) * H_ + (k - E_);
        glds16(src, ldst + u * 512);
      }
    };

    stage(0, 0); stage(1, 1); stage(2, 2); stage(3, 3);   // 8 loads in flight
    f32x16 acc0 = {}, acc1 = {};

#define KSTEP(c, buf, WAITS, DOSTAGE) do {                                   \
    asm volatile("s_waitcnt vmcnt(" WAITS ")" ::: "memory");                 \
    const u16* ab = awbase + (buf) * 1024;                                   \
    bf16x8 a0 = *(const bf16x8*)&ab[(((l >> 5)    ) * 32 + (l & 31)) * 8];   \
    bf16x8 a1 = *(const bf16x8*)&ab[(((l >> 5) + 2) * 32 + (l & 31)) * 8];   \
    acc0 = __builtin_amdgcn_mfma_f32_32x32x16_bf16(a0, Bf[2*(c)],   acc0, 0,0,0); \
    acc1 = __builtin_amdgcn_mfma_f32_32x32x16_bf16(a1, Bf[2*(c)+1], acc1, 0,0,0); \
    __builtin_amdgcn_sched_barrier(0);                                       \
    if (DOSTAGE) stage((c) + 4, (buf));                                      \
  } while (0)

    KSTEP(0, 0, "6", 1);  KSTEP(1, 1, "6", 1);  KSTEP(2, 2, "6", 1);
    KSTEP(3, 3, "6", 1);  KSTEP(4, 0, "6", 1);  KSTEP(5, 1, "6", 1);
    KSTEP(6, 2, "6", 1);  KSTEP(7, 3, "6", 1);
    KSTEP(8, 0, "6", 0);  KSTEP(9, 1, "4", 0);
    KSTEP(10, 2, "2", 0); KSTEP(11, 3, "0", 0);
#undef KSTEP

    acc0 += acc1;   // even/odd K-step partial accumulators

    // write partial tile to LDS: D col = l&31, row = (reg&3)+8*(reg>>2)+4*(l>>5)
    {
      float* pw = &pacc[w * 1152 + (l & 31) * 36 + 4 * (l >> 5)];
      *(f32x4*)&pw[0]  = f32x4{acc0[0],  acc0[1],  acc0[2],  acc0[3]};
      *(f32x4*)&pw[8]  = f32x4{acc0[4],  acc0[5],  acc0[6],  acc0[7]};
      *(f32x4*)&pw[16] = f32x4{acc0[8],  acc0[9],  acc0[10], acc0[11]};
      *(f32x4*)&pw[24] = f32x4{acc0[12], acc0[13], acc0[14], acc0[15]};
    }
    __syncthreads();

    // epilogue: sum 4 K-quarter partials + tb, activations, cx/hx update
    {
      float g4[4];
#pragma unroll
      for (int gi = 0; gi < 4; ++gi) {
        float s = tbr[gi];
#pragma unroll
        for (int k2 = 0; k2 < 4; ++k2)
          s += pacc[(k2 * 2 + mtE) * 1152 + (gi * 8 + hc) * 36 + rowE];
        g4[gi] = s;
      }
      float iv = fsigmoid(g4[0]);
      float fv = fsigmoid(g4[1]);
      float gv = ftanh(g4[2]);
      float ov = fsigmoid(g4[3]);
      float cn = fv * cx + iv * gv;
      cx = cn;
      float hn = ov * ftanh(cn);
      hout[(size_t)mglob * H_ + j * 8 + hc] = f2bf(hn);
    }
    gridbar(cnt, (unsigned)(t + 1) * NBLK);
  }
}

// ---------------------------------------------------------------- fc1 + BN
__global__ void fc1_bn(const u16* __restrict__ hxf, const float* __restrict__ w,
                       const float* __restrict__ bvec, const float* __restrict__ gamma,
                       const float* __restrict__ beta, float* __restrict__ h1n) {
  const int f = blockIdx.x;
  const int m = threadIdx.x;
  __shared__ float wrow[H_];
  __shared__ float red[128];
  for (int k = m; k < H_; k += 128) wrow[k] = w[(size_t)f * H_ + k];
  __syncthreads();
  float s = bvec[f];
  const u16* hr = &hxf[(size_t)m * H_];
  for (int k = 0; k < H_; k += 4) {
    ushort4 h4 = *(const ushort4*)&hr[k];
    s += bf2f(h4.x) * wrow[k] + bf2f(h4.y) * wrow[k + 1] +
         bf2f(h4.z) * wrow[k + 2] + bf2f(h4.w) * wrow[k + 3];
  }
  red[m] = s;
  __syncthreads();
  for (int off = 64; off > 0; off >>= 1) {
    if (m < off) red[m] += red[m + off];
    __syncthreads();
  }
  float mu = red[0] * (1.f / 128.f);
  __syncthreads();
  float d = s - mu;
  red[m] = d * d;
  __syncthreads();
  for (int off = 64; off > 0; off >>= 1) {
    if (m < off) red[m] += red[m + off];
    __syncthreads();
  }
  float var = red[0] * (1.f / 128.f);
  h1n[(size_t)m * F_ + f] = d * rsqrtf(var + 1e-5f) * gamma[f] + beta[f];
}

// ---------------------------------------------------------------- fc2
__global__ void fc2k(const float* __restrict__ h1n, const float* __restrict__ w,
                     const float* __restrict__ bvec, float* __restrict__ out) {
  int id = blockIdx.x * 256 + threadIdx.x;   // 1280 total
  if (id >= B_ * O_) return;
  int m = id / O_;
  int o = id - m * O_;
  float s = bvec[o];
  const float* hr = &h1n[(size_t)m * F_];
  const float* wr = &w[(size_t)o * F_];
#pragma unroll 8
  for (int k = 0; k < F_; ++k) s += hr[k] * wr[k];
  out[(size_t)m * O_ + o] = s;
}

// ---------------------------------------------------------------- launch
extern "C" void kernel_launch(void* const* d_in, const int* in_sizes, int n_in,
                              void* d_out, int out_size, void* d_ws, size_t ws_size,
                              hipStream_t stream) {
  const int*   x     = (const int*)  d_in[0];
  const float* x_top = (const float*)d_in[1];
  const float* emb   = (const float*)d_in[2];
  const float* w_ih  = (const float*)d_in[3];
  const float* w_hh  = (const float*)d_in[4];
  const float* w_th  = (const float*)d_in[5];
  const float* bvec  = (const float*)d_in[6];
  const float* fc1_w = (const float*)d_in[7];
  const float* fc1_b = (const float*)d_in[8];
  const float* gamma = (const float*)d_in[9];
  const float* beta  = (const float*)d_in[10];
  const float* fc2_w = (const float*)d_in[11];
  const float* fc2_b = (const float*)d_in[12];
  float* out = (float*)d_out;

  // ws layout (bytes)
  const size_t OFF_XE  = 0;           // 33,554,432  xe16 [T][B][E] bf16
  const size_t OFF_TB  = 33554432;    //  2,097,152  tb   [B][4H] f32
  const size_t OFF_HX0 = 35651584;    //    262,144  hx ping bf16
  const size_t OFF_HX1 = 35913728;    //    262,144  hx pong bf16
  const size_t OFF_CNT = 36175872;    //      4,096  barrier counter
  const size_t OFF_H1  = 36179968;    //    262,144  h1n [B][F] f32
  const size_t NEED    = 36442112;
  if (!d_ws || ws_size < NEED) return;

  char* ws = (char*)d_ws;
  u16*      xe16 = (u16*)(ws + OFF_XE);
  float*    tb   = (float*)(ws + OFF_TB);
  u16*      hx0  = (u16*)(ws + OFF_HX0);
  u16*      hx1  = (u16*)(ws + OFF_HX1);
  unsigned* cnt  = (unsigned*)(ws + OFF_CNT);
  float*    h1n  = (float*)(ws + OFF_H1);

  // zero hx0, hx1, barrier counter (contiguous)
  hipMemsetAsync(ws + OFF_HX0, 0, 262144 * 2 + 4096, stream);

  build_xe<<<16384, 256, 0, stream>>>(x, emb, xe16);
  topicb<<<128, 256, 0, stream>>>(x_top, w_th, bvec, tb);

  {
    const u16* a0 = xe16;
    u16* a1 = hx0; u16* a2 = hx1;
    const float* a3 = w_ih; const float* a4 = w_hh; const float* a5 = tb;
    unsigned* a6 = cnt;
    void* args[] = { (void*)&a0, (void*)&a1, (void*)&a2, (void*)&a3,
                     (void*)&a4, (void*)&a5, (void*)&a6 };
    hipError_t e = hipLaunchCooperativeKernel((void*)lstm_persist, dim3(NBLK),
                                              dim3(512), args, 0, stream);
    if (e != hipSuccess) {
      // fallback: plain launch (256 blocks, 1/CU -> co-resident)
      lstm_persist<<<NBLK, 512, 0, stream>>>(xe16, hx0, hx1, w_ih, w_hh, tb, cnt);
    }
  }
  // T_=256 even -> final hx in hx0

  fc1_bn<<<F_, 128, 0, stream>>>(hx0, fc1_w, fc1_b, gamma, beta, h1n);
  fc2k<<<5, 256, 0, stream>>>(h1n, fc2_w, fc2_b, out);
}

// Round 6
// 2244.303 us; speedup vs baseline: 2.2987x; 2.2987x over previous
//
#include <hip/hip_runtime.h>
#include <hip/hip_bf16.h>
#include <cstdint>
#include <cstddef>

typedef unsigned short u16;
typedef __attribute__((ext_vector_type(8))) __bf16 bf16x8;
typedef __attribute__((ext_vector_type(4))) float f32x4;

#define B_   128
#define T_   256
#define E_   512
#define H_   1024
#define G4_  4096
#define F_   512
#define O_   10
#define NBLK 256
#define BPG  32      // blocks per batch-group (heuristically one XCD)

__device__ __forceinline__ u16 f2bf(float f) {
  unsigned int u = __float_as_uint(f);
  u += 0x7FFFu + ((u >> 16) & 1u);
  return (u16)(u >> 16);
}
__device__ __forceinline__ float bf2f(u16 h) {
  return __uint_as_float(((unsigned int)h) << 16);
}
__device__ __forceinline__ float fsigmoid(float x) {
  return 1.f / (1.f + __expf(-x));
}
__device__ __forceinline__ float ftanh(float x) {
  float ax = fabsf(x);
  float t = __expf(-2.f * ax);
  float r = (1.f - t) / (1.f + t);
  return copysignf(r, x);
}
__device__ __forceinline__ bf16x8 pack8(float4 f0, float4 f1) {
  union { bf16x8 v; u16 s[8]; } uu;
  uu.s[0] = f2bf(f0.x); uu.s[1] = f2bf(f0.y); uu.s[2] = f2bf(f0.z); uu.s[3] = f2bf(f0.w);
  uu.s[4] = f2bf(f1.x); uu.s[5] = f2bf(f1.y); uu.s[6] = f2bf(f1.z); uu.s[7] = f2bf(f1.w);
  return uu.v;
}

// async global->LDS, 16B per lane; lds dest = wave-uniform base + lane*16
__device__ __forceinline__ void glds16(const void* g, void* l) {
  __builtin_amdgcn_global_load_lds(
      (const __attribute__((address_space(1))) unsigned int*)g,
      (__attribute__((address_space(3))) unsigned int*)l, 16, 0, 0);
}

// ---------------------------------------------------------------- build xe16
// xe16[t*B+b][e] = bf16(emb[x[b][t]][e])
__global__ void build_xe(const int* __restrict__ x, const float* __restrict__ emb,
                         u16* __restrict__ xe16) {
  int id = blockIdx.x * 256 + threadIdx.x;
  int row = id >> 7;                          // b*T + t
  int c = (id & 127) << 2;
  int v = x[row];
  int b = row >> 8;
  int t = row & 255;
  const float4 f = *(const float4*)&emb[(size_t)v * E_ + c];
  ushort4 o;
  o.x = f2bf(f.x); o.y = f2bf(f.y); o.z = f2bf(f.z); o.w = f2bf(f.w);
  *(ushort4*)&xe16[((size_t)(t * B_ + b)) * E_ + c] = o;
}

// ---------------------------------------------------------------- topic bias
__global__ void topicb(const float* __restrict__ x_top, const float* __restrict__ w_th,
                       const float* __restrict__ bias, float* __restrict__ tb) {
  int m = blockIdx.x;
  __shared__ float xt[128];
  if (threadIdx.x < 128) xt[threadIdx.x] = x_top[m * 128 + threadIdx.x];
  __syncthreads();
  for (int g = threadIdx.x; g < G4_; g += 256) {
    const float* wr = &w_th[(size_t)g * 128];
    float s = bias[g];
#pragma unroll 8
    for (int k = 0; k < 128; ++k) s += xt[k] * wr[k];
    tb[(size_t)m * G4_ + g] = s;
  }
}

// ---------------------------------------------------------------- group barrier
__device__ __forceinline__ void groupbar(unsigned* cnt, unsigned target) {
  __syncthreads();   // drains all waves' vm/lgkm (incl. hout stores) + block sync
  if (threadIdx.x == 0) {
    __hip_atomic_fetch_add(cnt, 1u, __ATOMIC_RELEASE, __HIP_MEMORY_SCOPE_AGENT);
    while (__hip_atomic_load(cnt, __ATOMIC_RELAXED, __HIP_MEMORY_SCOPE_AGENT) < target)
      __builtin_amdgcn_s_sleep(1);
    (void)__hip_atomic_load(cnt, __ATOMIC_ACQUIRE, __HIP_MEMORY_SCOPE_AGENT);
  }
  __syncthreads();
}

// ---------------------------------------------------------------- persistent LSTM
// 256 blocks x 512 threads (1 block/CU). Group g = bid&7 owns batch rows
// [16g,16g+16); block c = bid>>3 owns h-cols [32c,32c+32). Wave w =
// (gate = w>>1, hsub = w&1): 16 gate-cols, full K=1536, with its entire
// weight slice in 48 bf16x8 register fragments (192 VGPR). A (xe_t|hx_t)
// staged once per step into LDS (no reuse => no races): xe ping-pong
// prefetched one step ahead, hx staged at step start and consumed after a
// counted vmcnt(2) + raw barrier. cx and tb in registers.
__global__ __launch_bounds__(512, 2) void lstm_persist(
    const u16* __restrict__ xe, u16* __restrict__ h0, u16* __restrict__ h1,
    const float* __restrict__ wih, const float* __restrict__ whh,
    const float* __restrict__ tb, unsigned* __restrict__ cnt) {
  // A LDS layout, per 64-k chunk (1024 u16): row r (0..15), slot s (0..7):
  // u16 off = r*64 + (s ^ (r&7))*8 holds A[r][chunk*64 + (s^(r&7))*8 ...]
  // i.e. linear DMA dest + pre-swizzled global source; reads use same XOR.
  __shared__ __align__(16) u16 Axe[2][8192];   // 2 x 8 chunks (xe ping-pong)
  __shared__ __align__(16) u16 Ahx[16384];     // 16 chunks (hx)
  __shared__ __align__(16) float pacc[128 * 20];

  const int bid = blockIdx.x;
  const int g = bid & 7;
  const int cblk = bid >> 3;
  const int hcb = cblk * 32;
  const int g16 = g * 16;
  const int tid = threadIdx.x;
  const int w = tid >> 6, l = tid & 63;
  const int qq = l >> 4;          // k-quarter within 32-k MFMA window
  const int r16 = l & 15;         // A row / D col lane position
  const int lx7 = l & 7;          // XOR swizzle key (= r16 & 7)
  unsigned* cntg = cnt + g * 64;  // 256B-spaced per-group counters

  // ---- one-time: full W slice (16 rows x 1536) into 48 register fragments
  const int grow = (w >> 1) * H_ + hcb + (w & 1) * 16 + r16;
  bf16x8 Bf[48];
#pragma unroll
  for (int kk = 0; kk < 48; ++kk) {
    int k = kk * 32 + qq * 8;
    const float* sp = (k < E_) ? (wih + (size_t)grow * E_ + k)
                               : (whh + (size_t)grow * H_ + (k - E_));
    Bf[kk] = pack8(*(const float4*)sp, *(const float4*)(sp + 4));
  }

  // ---- epilogue cell: row = tid>>5 (batch row), hc = tid&31 (local h-col)
  const int erow = tid >> 5, ehc = tid & 31;
  const int mglob = g16 + erow;
  float tbr[4];
#pragma unroll
  for (int gi = 0; gi < 4; ++gi)
    tbr[gi] = tb[(size_t)mglob * G4_ + gi * H_ + hcb + ehc];
  float cx = 0.f;

  // staging: wave w owns xe chunk w (2 loads) and hx chunks 2w,2w+1 (4 loads)
  auto stage_xe = [&](int tn) {
#pragma unroll
    for (int i = 0; i < 2; ++i) {
      int rl = i * 8 + (l >> 3);
      int sw = ((l & 7) ^ (l >> 3)) << 3;
      const u16* src = xe + ((size_t)(tn * B_ + g16 + rl)) * E_ + (w << 6) + sw;
      glds16(src, (char*)Axe[tn & 1] + w * 2048 + i * 1024);
    }
  };
  auto stage_hx = [&](const u16* hin) {
#pragma unroll
    for (int ii = 0; ii < 4; ++ii) {
      int ch = 2 * w + (ii >> 1);
      int i = ii & 1;
      int rl = i * 8 + (l >> 3);
      int sw = ((l & 7) ^ (l >> 3)) << 3;
      const u16* src = hin + (size_t)(g16 + rl) * H_ + (ch << 6) + sw;
      glds16(src, (char*)Ahx + ch * 2048 + i * 1024);
    }
  };

  stage_xe(0);
  __syncthreads();   // drains own DMA (and Bf loads); Axe[0] visible to all

  for (int t = 0; t < T_; ++t) {
    const u16* hin  = (t & 1) ? h1 : h0;
    u16*       hout = (t & 1) ? h0 : h1;

    stage_hx(hin);                       // 4 loads; lands under xe compute

    f32x4 acc[4] = {{}, {}, {}, {}};
    const u16* axe = Axe[t & 1];
    // xe part: K-steps 0..15 (Axe visible since last step's groupbar sync)
#pragma unroll
    for (int kk = 0; kk < 16; ++kk) {
      bf16x8 a = *(const bf16x8*)&axe[(kk >> 1) * 1024 + r16 * 64 +
                                      ((((kk & 1) * 4 + qq) ^ lx7) << 3)];
      acc[kk & 3] = __builtin_amdgcn_mfma_f32_16x16x32_bf16(a, Bf[kk], acc[kk & 3], 0, 0, 0);
    }
    stage_xe((t + 1) & 255);             // 2 loads; lands during next step

    // own FIFO: [4 hx][2 xe] outstanding -> vmcnt(2) == my hx landed;
    // barrier -> every wave's hx landed (each drained its own pre-barrier)
    asm volatile("s_waitcnt vmcnt(2)" ::: "memory");
    __builtin_amdgcn_s_barrier();
    __builtin_amdgcn_sched_barrier(0);

    // hx part: K-steps 16..47
#pragma unroll
    for (int kk = 16; kk < 48; ++kk) {
      bf16x8 a = *(const bf16x8*)&Ahx[((kk - 16) >> 1) * 1024 + r16 * 64 +
                                      ((((kk & 1) * 4 + qq) ^ lx7) << 3)];
      acc[kk & 3] = __builtin_amdgcn_mfma_f32_16x16x32_bf16(a, Bf[kk], acc[kk & 3], 0, 0, 0);
    }
    f32x4 accs = (acc[0] + acc[1]) + (acc[2] + acc[3]);

    // partials -> pacc: D col = r16 (wave-local gate col), row = qq*4+rr
    *(f32x4*)&pacc[((w >> 1) * 32 + (w & 1) * 16 + r16) * 20 + qq * 4] = accs;
    asm volatile("s_waitcnt lgkmcnt(0)" ::: "memory");
    __builtin_amdgcn_s_barrier();
    __builtin_amdgcn_sched_barrier(0);

    // epilogue: one (batch-row, h-col) cell per thread; i,f,g,o across pacc
    {
      float g4[4];
#pragma unroll
      for (int gi = 0; gi < 4; ++gi)
        g4[gi] = pacc[(gi * 32 + ehc) * 20 + erow] + tbr[gi];
      float iv = fsigmoid(g4[0]);
      float fv = fsigmoid(g4[1]);
      float gv = ftanh(g4[2]);
      float ov = fsigmoid(g4[3]);
      float cn = fv * cx + iv * gv;
      cx = cn;
      float hn = ov * ftanh(cn);
      hout[(size_t)mglob * H_ + hcb + ehc] = f2bf(hn);
    }
    groupbar(cntg, (unsigned)(t + 1) * BPG);
  }
}

// ---------------------------------------------------------------- fc1 + BN
__global__ void fc1_bn(const u16* __restrict__ hxf, const float* __restrict__ w,
                       const float* __restrict__ bvec, const float* __restrict__ gamma,
                       const float* __restrict__ beta, float* __restrict__ h1n) {
  const int f = blockIdx.x;
  const int m = threadIdx.x;
  __shared__ float wrow[H_];
  __shared__ float red[128];
  for (int k = m; k < H_; k += 128) wrow[k] = w[(size_t)f * H_ + k];
  __syncthreads();
  float s = bvec[f];
  const u16* hr = &hxf[(size_t)m * H_];
  for (int k = 0; k < H_; k += 4) {
    ushort4 h4 = *(const ushort4*)&hr[k];
    s += bf2f(h4.x) * wrow[k] + bf2f(h4.y) * wrow[k + 1] +
         bf2f(h4.z) * wrow[k + 2] + bf2f(h4.w) * wrow[k + 3];
  }
  red[m] = s;
  __syncthreads();
  for (int off = 64; off > 0; off >>= 1) {
    if (m < off) red[m] += red[m + off];
    __syncthreads();
  }
  float mu = red[0] * (1.f / 128.f);
  __syncthreads();
  float d = s - mu;
  red[m] = d * d;
  __syncthreads();
  for (int off = 64; off > 0; off >>= 1) {
    if (m < off) red[m] += red[m + off];
    __syncthreads();
  }
  float var = red[0] * (1.f / 128.f);
  h1n[(size_t)m * F_ + f] = d * rsqrtf(var + 1e-5f) * gamma[f] + beta[f];
}

// ---------------------------------------------------------------- fc2
__global__ void fc2k(const float* __restrict__ h1n, const float* __restrict__ w,
                     const float* __restrict__ bvec, float* __restrict__ out) {
  int id = blockIdx.x * 256 + threadIdx.x;
  if (id >= B_ * O_) return;
  int m = id / O_;
  int o = id - m * O_;
  float s = bvec[o];
  const float* hr = &h1n[(size_t)m * F_];
  const float* wr = &w[(size_t)o * F_];
#pragma unroll 8
  for (int k = 0; k < F_; ++k) s += hr[k] * wr[k];
  out[(size_t)m * O_ + o] = s;
}

// ---------------------------------------------------------------- launch
extern "C" void kernel_launch(void* const* d_in, const int* in_sizes, int n_in,
                              void* d_out, int out_size, void* d_ws, size_t ws_size,
                              hipStream_t stream) {
  const int*   x     = (const int*)  d_in[0];
  const float* x_top = (const float*)d_in[1];
  const float* emb   = (const float*)d_in[2];
  const float* w_ih  = (const float*)d_in[3];
  const float* w_hh  = (const float*)d_in[4];
  const float* w_th  = (const float*)d_in[5];
  const float* bvec  = (const float*)d_in[6];
  const float* fc1_w = (const float*)d_in[7];
  const float* fc1_b = (const float*)d_in[8];
  const float* gamma = (const float*)d_in[9];
  const float* beta  = (const float*)d_in[10];
  const float* fc2_w = (const float*)d_in[11];
  const float* fc2_b = (const float*)d_in[12];
  float* out = (float*)d_out;

  // ws layout (bytes)
  const size_t OFF_XE  = 0;           // 33,554,432  xe16 [T][B][E] bf16
  const size_t OFF_TB  = 33554432;    //  2,097,152  tb   [B][4H] f32
  const size_t OFF_HX0 = 35651584;    //    262,144  hx ping bf16
  const size_t OFF_HX1 = 35913728;    //    262,144  hx pong bf16
  const size_t OFF_CNT = 36175872;    //      4,096  8 group counters (256B apart)
  const size_t OFF_H1  = 36179968;    //    262,144  h1n [B][F] f32
  const size_t NEED    = 36442112;
  if (!d_ws || ws_size < NEED) return;

  char* ws = (char*)d_ws;
  u16*      xe16 = (u16*)(ws + OFF_XE);
  float*    tb   = (float*)(ws + OFF_TB);
  u16*      hx0  = (u16*)(ws + OFF_HX0);
  u16*      hx1  = (u16*)(ws + OFF_HX1);
  unsigned* cnt  = (unsigned*)(ws + OFF_CNT);
  float*    h1n  = (float*)(ws + OFF_H1);

  // zero hx0, hx1, group counters (contiguous)
  hipMemsetAsync(ws + OFF_HX0, 0, 262144 * 2 + 4096, stream);

  build_xe<<<16384, 256, 0, stream>>>(x, emb, xe16);
  topicb<<<128, 256, 0, stream>>>(x_top, w_th, bvec, tb);

  // plain launch: 256 blocks = 1/CU, co-resident; groups sync independently
  lstm_persist<<<NBLK, 512, 0, stream>>>(xe16, hx0, hx1, w_ih, w_hh, tb, cnt);
  // T_=256 even -> final hx in hx0

  fc1_bn<<<F_, 128, 0, stream>>>(hx0, fc1_w, fc1_b, gamma, beta, h1n);
  fc2k<<<5, 256, 0, stream>>>(h1n, fc2_w, fc2_b, out);
}

// Round 7
// 1066.488 us; speedup vs baseline: 4.8373x; 2.1044x over previous
//
#include <hip/hip_runtime.h>
#include <hip/hip_bf16.h>
#include <cstdint>
#include <cstddef>

typedef unsigned short u16;
typedef __attribute__((ext_vector_type(8))) __bf16 bf16x8;
typedef __attribute__((ext_vector_type(4))) float f32x4;

#define B_   128
#define T_   256
#define E_   512
#define H_   1024
#define G4_  4096
#define F_   512
#define O_   10
#define NBLK 256
#define BPG  32      // blocks per batch-group (heuristically one XCD)

__device__ __forceinline__ u16 f2bf(float f) {
  unsigned int u = __float_as_uint(f);
  u += 0x7FFFu + ((u >> 16) & 1u);
  return (u16)(u >> 16);
}
__device__ __forceinline__ float bf2f(u16 h) {
  return __uint_as_float(((unsigned int)h) << 16);
}
__device__ __forceinline__ float fsigmoid(float x) {
  return 1.f / (1.f + __expf(-x));
}
__device__ __forceinline__ float ftanh(float x) {
  float ax = fabsf(x);
  float t = __expf(-2.f * ax);
  float r = (1.f - t) / (1.f + t);
  return copysignf(r, x);
}
__device__ __forceinline__ bf16x8 pack8(float4 f0, float4 f1) {
  union { bf16x8 v; u16 s[8]; } uu;
  uu.s[0] = f2bf(f0.x); uu.s[1] = f2bf(f0.y); uu.s[2] = f2bf(f0.z); uu.s[3] = f2bf(f0.w);
  uu.s[4] = f2bf(f1.x); uu.s[5] = f2bf(f1.y); uu.s[6] = f2bf(f1.z); uu.s[7] = f2bf(f1.w);
  return uu.v;
}

// async global->LDS, 16B per lane; lds dest = wave-uniform base + lane*16
__device__ __forceinline__ void glds16(const void* g, void* l) {
  __builtin_amdgcn_global_load_lds(
      (const __attribute__((address_space(1))) unsigned int*)g,
      (__attribute__((address_space(3))) unsigned int*)l, 16, 0, 0);
}
// coherent variant: aux = sc0|sc1 (1|16) -> bypass L1/L2, read at LLC.
// Used for hx (written by other blocks, possibly other XCDs).
__device__ __forceinline__ void glds16_coh(const void* g, void* l) {
  __builtin_amdgcn_global_load_lds(
      (const __attribute__((address_space(1))) unsigned int*)g,
      (__attribute__((address_space(3))) unsigned int*)l, 16, 0, 17);
}

// ---------------------------------------------------------------- build xe16
// xe16[t*B+b][e] = bf16(emb[x[b][t]][e])
__global__ void build_xe(const int* __restrict__ x, const float* __restrict__ emb,
                         u16* __restrict__ xe16) {
  int id = blockIdx.x * 256 + threadIdx.x;
  int row = id >> 7;                          // b*T + t
  int c = (id & 127) << 2;
  int v = x[row];
  int b = row >> 8;
  int t = row & 255;
  const float4 f = *(const float4*)&emb[(size_t)v * E_ + c];
  ushort4 o;
  o.x = f2bf(f.x); o.y = f2bf(f.y); o.z = f2bf(f.z); o.w = f2bf(f.w);
  *(ushort4*)&xe16[((size_t)(t * B_ + b)) * E_ + c] = o;
}

// ---------------------------------------------------------------- topic bias
__global__ void topicb(const float* __restrict__ x_top, const float* __restrict__ w_th,
                       const float* __restrict__ bias, float* __restrict__ tb) {
  int m = blockIdx.x;
  __shared__ float xt[128];
  if (threadIdx.x < 128) xt[threadIdx.x] = x_top[m * 128 + threadIdx.x];
  __syncthreads();
  for (int g = threadIdx.x; g < G4_; g += 256) {
    const float* wr = &w_th[(size_t)g * 128];
    float s = bias[g];
#pragma unroll 8
    for (int k = 0; k < 128; ++k) s += xt[k] * wr[k];
    tb[(size_t)m * G4_ + g] = s;
  }
}

// ---------------------------------------------------------------- group barrier
// FENCE-FREE: data (hx) goes through the coherent point explicitly
// (sc1 stores / sc1 DMA loads), so no L2 writeback/invalidate is needed.
// __syncthreads drains vmcnt => my sc1 stores are at LLC before my add.
__device__ __forceinline__ void groupbar(unsigned* cnt, unsigned target) {
  __syncthreads();
  if (threadIdx.x == 0) {
    __hip_atomic_fetch_add(cnt, 1u, __ATOMIC_RELAXED, __HIP_MEMORY_SCOPE_AGENT);
    while (__hip_atomic_load(cnt, __ATOMIC_RELAXED, __HIP_MEMORY_SCOPE_AGENT) < target)
      __builtin_amdgcn_s_sleep(1);
  }
  __syncthreads();
}

// ---------------------------------------------------------------- persistent LSTM
// 256 blocks x 512 threads (1 block/CU). Group g = bid&7 owns batch rows
// [16g,16g+16); block c = bid>>3 owns h-cols [32c,32c+32). Wave w =
// (gate = w>>1, hsub = w&1): 16 gate-cols, full K=1536, entire weight
// slice in 48 bf16x8 register fragments. A (xe_t|hx_t) staged once per
// step into LDS (no buffer reuse => no races): xe ping-pong prefetched one
// step ahead (cached), hx staged at step start via COHERENT (sc0|sc1) DMA
// and consumed after counted vmcnt(2) + raw barrier. cx/tb in registers.
__global__ __launch_bounds__(512, 2) void lstm_persist(
    const u16* __restrict__ xe, u16* __restrict__ h0, u16* __restrict__ h1,
    const float* __restrict__ wih, const float* __restrict__ whh,
    const float* __restrict__ tb, unsigned* __restrict__ cnt) {
  // A LDS layout, per 64-k chunk (1024 u16): row r (0..15), slot s (0..7):
  // u16 off = r*64 + (s ^ (r&7))*8  (linear DMA dest + pre-swizzled global
  // source; reads use the same XOR) -> conflict-free ds_read_b128.
  __shared__ __align__(16) u16 Axe[2][8192];   // 2 x 8 chunks (xe ping-pong)
  __shared__ __align__(16) u16 Ahx[16384];     // 16 chunks (hx)
  __shared__ __align__(16) float pacc[128 * 20];

  const int bid = blockIdx.x;
  const int g = bid & 7;
  const int cblk = bid >> 3;
  const int hcb = cblk * 32;
  const int g16 = g * 16;
  const int tid = threadIdx.x;
  const int w = tid >> 6, l = tid & 63;
  const int qq = l >> 4;          // k-quarter within 32-k MFMA window
  const int r16 = l & 15;         // A row / D col lane position
  const int lx7 = l & 7;          // XOR swizzle key
  unsigned* cntg = cnt + g * 64;  // 256B-spaced per-group counters

  // ---- one-time: full W slice (16 rows x 1536) into 48 register fragments
  const int grow = (w >> 1) * H_ + hcb + (w & 1) * 16 + r16;
  bf16x8 Bf[48];
#pragma unroll
  for (int kk = 0; kk < 48; ++kk) {
    int k = kk * 32 + qq * 8;
    const float* sp = (k < E_) ? (wih + (size_t)grow * E_ + k)
                               : (whh + (size_t)grow * H_ + (k - E_));
    Bf[kk] = pack8(*(const float4*)sp, *(const float4*)(sp + 4));
  }

  // ---- epilogue cell: row = tid>>5 (batch row), hc = tid&31 (local h-col)
  const int erow = tid >> 5, ehc = tid & 31;
  const int mglob = g16 + erow;
  float tbr[4];
#pragma unroll
  for (int gi = 0; gi < 4; ++gi)
    tbr[gi] = tb[(size_t)mglob * G4_ + gi * H_ + hcb + ehc];
  float cx = 0.f;

  // staging: wave w owns xe chunk w (2 loads) and hx chunks 2w,2w+1 (4 loads)
  auto stage_xe = [&](int tn) {
#pragma unroll
    for (int i = 0; i < 2; ++i) {
      int rl = i * 8 + (l >> 3);
      int sw = ((l & 7) ^ (l >> 3)) << 3;
      const u16* src = xe + ((size_t)(tn * B_ + g16 + rl)) * E_ + (w << 6) + sw;
      glds16(src, (char*)Axe[tn & 1] + w * 2048 + i * 1024);
    }
  };
  auto stage_hx = [&](const u16* hin) {
#pragma unroll
    for (int ii = 0; ii < 4; ++ii) {
      int ch = 2 * w + (ii >> 1);
      int i = ii & 1;
      int rl = i * 8 + (l >> 3);
      int sw = ((l & 7) ^ (l >> 3)) << 3;
      const u16* src = hin + (size_t)(g16 + rl) * H_ + (ch << 6) + sw;
      glds16_coh(src, (char*)Ahx + ch * 2048 + i * 1024);   // coherent read
    }
  };

  stage_xe(0);
  __syncthreads();   // drains own DMA; Axe[0] visible to all waves

  for (int t = 0; t < T_; ++t) {
    const u16* hin  = (t & 1) ? h1 : h0;
    u16*       hout = (t & 1) ? h0 : h1;

    stage_hx(hin);                       // 4 coherent loads; land under xe MFMAs

    f32x4 acc[4] = {{}, {}, {}, {}};
    const u16* axe = Axe[t & 1];
    // xe part: K-steps 0..15
#pragma unroll
    for (int kk = 0; kk < 16; ++kk) {
      bf16x8 a = *(const bf16x8*)&axe[(kk >> 1) * 1024 + r16 * 64 +
                                      ((((kk & 1) * 4 + qq) ^ lx7) << 3)];
      acc[kk & 3] = __builtin_amdgcn_mfma_f32_16x16x32_bf16(a, Bf[kk], acc[kk & 3], 0, 0, 0);
    }
    stage_xe((t + 1) & 255);             // 2 cached loads; land during next step

    // own FIFO: [4 hx][2 xe] outstanding -> vmcnt(2) == my hx landed;
    // raw barrier -> every wave's hx landed (each drained its own before it)
    asm volatile("s_waitcnt vmcnt(2)" ::: "memory");
    __builtin_amdgcn_s_barrier();
    __builtin_amdgcn_sched_barrier(0);

    // hx part: K-steps 16..47
#pragma unroll
    for (int kk = 16; kk < 48; ++kk) {
      bf16x8 a = *(const bf16x8*)&Ahx[((kk - 16) >> 1) * 1024 + r16 * 64 +
                                      ((((kk & 1) * 4 + qq) ^ lx7) << 3)];
      acc[kk & 3] = __builtin_amdgcn_mfma_f32_16x16x32_bf16(a, Bf[kk], acc[kk & 3], 0, 0, 0);
    }
    f32x4 accs = (acc[0] + acc[1]) + (acc[2] + acc[3]);

    // partials -> pacc: D col = r16 (wave-local gate col), row = qq*4+rr
    *(f32x4*)&pacc[((w >> 1) * 32 + (w & 1) * 16 + r16) * 20 + qq * 4] = accs;
    asm volatile("s_waitcnt lgkmcnt(0)" ::: "memory");
    __builtin_amdgcn_s_barrier();
    __builtin_amdgcn_sched_barrier(0);

    // epilogue: one (batch-row, h-col) cell per thread; pack 2 cols -> u32,
    // store through the coherent point (agent-scope relaxed atomic store).
    {
      float g4[4];
#pragma unroll
      for (int gi = 0; gi < 4; ++gi)
        g4[gi] = pacc[(gi * 32 + ehc) * 20 + erow] + tbr[gi];
      float iv = fsigmoid(g4[0]);
      float fv = fsigmoid(g4[1]);
      float gv = ftanh(g4[2]);
      float ov = fsigmoid(g4[3]);
      float cn = fv * cx + iv * gv;
      cx = cn;
      float hn = ov * ftanh(cn);
      unsigned hb = (unsigned)f2bf(hn);
      unsigned pb = __shfl_xor(hb, 1);   // partner col within same row
      if ((ehc & 1) == 0) {
        unsigned pv = (pb << 16) | hb;   // even lane = low half
        __hip_atomic_store((unsigned*)(hout + (size_t)mglob * H_ + hcb + ehc),
                           pv, __ATOMIC_RELAXED, __HIP_MEMORY_SCOPE_AGENT);
      }
    }
    groupbar(cntg, (unsigned)(t + 1) * BPG);
  }
}

// ---------------------------------------------------------------- fc1 + BN
__global__ void fc1_bn(const u16* __restrict__ hxf, const float* __restrict__ w,
                       const float* __restrict__ bvec, const float* __restrict__ gamma,
                       const float* __restrict__ beta, float* __restrict__ h1n) {
  const int f = blockIdx.x;
  const int m = threadIdx.x;
  __shared__ float wrow[H_];
  __shared__ float red[128];
  for (int k = m; k < H_; k += 128) wrow[k] = w[(size_t)f * H_ + k];
  __syncthreads();
  float s = bvec[f];
  const u16* hr = &hxf[(size_t)m * H_];
  for (int k = 0; k < H_; k += 4) {
    ushort4 h4 = *(const ushort4*)&hr[k];
    s += bf2f(h4.x) * wrow[k] + bf2f(h4.y) * wrow[k + 1] +
         bf2f(h4.z) * wrow[k + 2] + bf2f(h4.w) * wrow[k + 3];
  }
  red[m] = s;
  __syncthreads();
  for (int off = 64; off > 0; off >>= 1) {
    if (m < off) red[m] += red[m + off];
    __syncthreads();
  }
  float mu = red[0] * (1.f / 128.f);
  __syncthreads();
  float d = s - mu;
  red[m] = d * d;
  __syncthreads();
  for (int off = 64; off > 0; off >>= 1) {
    if (m < off) red[m] += red[m + off];
    __syncthreads();
  }
  float var = red[0] * (1.f / 128.f);
  h1n[(size_t)m * F_ + f] = d * rsqrtf(var + 1e-5f) * gamma[f] + beta[f];
}

// ---------------------------------------------------------------- fc2
__global__ void fc2k(const float* __restrict__ h1n, const float* __restrict__ w,
                     const float* __restrict__ bvec, float* __restrict__ out) {
  int id = blockIdx.x * 256 + threadIdx.x;
  if (id >= B_ * O_) return;
  int m = id / O_;
  int o = id - m * O_;
  float s = bvec[o];
  const float* hr = &h1n[(size_t)m * F_];
  const float* wr = &w[(size_t)o * F_];
#pragma unroll 8
  for (int k = 0; k < F_; ++k) s += hr[k] * wr[k];
  out[(size_t)m * O_ + o] = s;
}

// ---------------------------------------------------------------- launch
extern "C" void kernel_launch(void* const* d_in, const int* in_sizes, int n_in,
                              void* d_out, int out_size, void* d_ws, size_t ws_size,
                              hipStream_t stream) {
  const int*   x     = (const int*)  d_in[0];
  const float* x_top = (const float*)d_in[1];
  const float* emb   = (const float*)d_in[2];
  const float* w_ih  = (const float*)d_in[3];
  const float* w_hh  = (const float*)d_in[4];
  const float* w_th  = (const float*)d_in[5];
  const float* bvec  = (const float*)d_in[6];
  const float* fc1_w = (const float*)d_in[7];
  const float* fc1_b = (const float*)d_in[8];
  const float* gamma = (const float*)d_in[9];
  const float* beta  = (const float*)d_in[10];
  const float* fc2_w = (const float*)d_in[11];
  const float* fc2_b = (const float*)d_in[12];
  float* out = (float*)d_out;

  // ws layout (bytes)
  const size_t OFF_XE  = 0;           // 33,554,432  xe16 [T][B][E] bf16
  const size_t OFF_TB  = 33554432;    //  2,097,152  tb   [B][4H] f32
  const size_t OFF_HX0 = 35651584;    //    262,144  hx ping bf16
  const size_t OFF_HX1 = 35913728;    //    262,144  hx pong bf16
  const size_t OFF_CNT = 36175872;    //      4,096  8 group counters (256B apart)
  const size_t OFF_H1  = 36179968;    //    262,144  h1n [B][F] f32
  const size_t NEED    = 36442112;
  if (!d_ws || ws_size < NEED) return;

  char* ws = (char*)d_ws;
  u16*      xe16 = (u16*)(ws + OFF_XE);
  float*    tb   = (float*)(ws + OFF_TB);
  u16*      hx0  = (u16*)(ws + OFF_HX0);
  u16*      hx1  = (u16*)(ws + OFF_HX1);
  unsigned* cnt  = (unsigned*)(ws + OFF_CNT);
  float*    h1n  = (float*)(ws + OFF_H1);

  // zero hx0, hx1, group counters (contiguous)
  hipMemsetAsync(ws + OFF_HX0, 0, 262144 * 2 + 4096, stream);

  build_xe<<<16384, 256, 0, stream>>>(x, emb, xe16);
  topicb<<<128, 256, 0, stream>>>(x_top, w_th, bvec, tb);

  // plain launch: 256 blocks = 1/CU, co-resident; groups sync independently
  lstm_persist<<<NBLK, 512, 0, stream>>>(xe16, hx0, hx1, w_ih, w_hh, tb, cnt);
  // T_=256 even -> final hx in hx0

  fc1_bn<<<F_, 128, 0, stream>>>(hx0, fc1_w, fc1_b, gamma, beta, h1n);
  fc2k<<<5, 256, 0, stream>>>(h1n, fc2_w, fc2_b, out);
}